// Round 1
// baseline (3253.425 us; speedup 1.0000x reference)
//
#include <hip/hip_runtime.h>
#include <cstddef>

// ---------------------------------------------------------------------------
// RSSM (Dreamer) observe:  T=64 sequential steps, B=1024, S=30, D=H=200,
// E=1024, A=6.  Output [B,T,580] fp32.
//
// Plan:
//   K0: convert + transpose all weights to bf16 into d_ws (one-shot, ~10us)
//   K1: precompute embed part of obs1:  xpre[t][b][h] = embed[b,t,:] @
//       w_obs1[200:1224,:] + b_obs1   (bf16 MFMA 16x16x32, BM=64, BN=208)
//   K2: persistent recurrent kernel, 256 WGs x 4 batch rows, 512 threads,
//       state in LDS, bf16 weights streamed from L2, fp32 VALU FMA.
//
// ws layout (bytes):
//   [0 .. 425984)        wT_obs1  bf16 [208][1024]   (K1 B operand, n-major)
//   [425984 .. 1128384)  transposed recurrent weights bf16 (see offsets)
//   [1128384 .. 53557184) xpre fp32 [64][1024][200]
// total 53,557,184 B required of ws_size.
// ---------------------------------------------------------------------------

typedef __bf16 bf16x8 __attribute__((ext_vector_type(8)));
typedef float  f32x4  __attribute__((ext_vector_type(4)));

#define WS_W1T     212992   // [200][36]
#define WS_GWT     220192   // [600][200]
#define WS_GUT     340192   // [600][200]
#define WS_W2T     460192   // [200][200]
#define WS_WODT    500192   // [200][200]
#define WS_WIMT    540192   // [30][200]
#define WS_WIST    546192   // [30][200]
#define WS_WOMT    552192   // [30][200]
#define WS_WOST    558192   // [30][200]
#define WS_TOTAL_BF 564192
#define WS_XPRE_BYTES 1128384

__device__ __forceinline__ float elu1(float v){ return v > 0.f ? v : expm1f(v); }
__device__ __forceinline__ float sigm(float v){ return 1.f / (1.f + expf(-v)); }
__device__ __forceinline__ float spls(float v){ return fmaxf(v,0.f) + log1pf(expf(-fabsf(v))); }

// ---------------------------------------------------------------------------
// K0: weight conversion/transpose to bf16.
// Output layouts are all k-contiguous rows so K2 threads read 16B chunks.
// ---------------------------------------------------------------------------
__global__ __launch_bounds__(256) void k0_convert(
    const float* __restrict__ w_img1, const float* __restrict__ gru_w,
    const float* __restrict__ gru_u,  const float* __restrict__ w_img2,
    const float* __restrict__ w_imean, const float* __restrict__ w_istd,
    const float* __restrict__ w_obs1, const float* __restrict__ w_omean,
    const float* __restrict__ w_ostd, __bf16* __restrict__ o)
{
  int i = blockIdx.x * 256 + threadIdx.x;
  float v;
  if (i < 212992) {                       // wT_obs1[n][k] = w_obs1[200+k][n]
    int n = i >> 10, k = i & 1023;
    v = (n < 200) ? w_obs1[(size_t)(200 + k) * 200 + n] : 0.f;
  } else if (i < WS_GWT) {                // w1T[h][k] = w_img1[k][h]
    int q = i - WS_W1T; int h = q / 36, k = q - h * 36;
    v = w_img1[k * 200 + h];
  } else if (i < WS_GUT) {                // gwT[j][k] = gru_w[k][j]
    int q = i - WS_GWT; int j = q / 200, k = q - j * 200;
    v = gru_w[k * 600 + j];
  } else if (i < WS_W2T) {                // guT[j][k] = gru_u[k][j]
    int q = i - WS_GUT; int j = q / 200, k = q - j * 200;
    v = gru_u[k * 600 + j];
  } else if (i < WS_WODT) {               // w2T[h][k] = w_img2[k][h]
    int q = i - WS_W2T; int h = q / 200, k = q - h * 200;
    v = w_img2[k * 200 + h];
  } else if (i < WS_WIMT) {               // wodT[h][k] = w_obs1[k][h] (deter part)
    int q = i - WS_WODT; int h = q / 200, k = q - h * 200;
    v = w_obs1[k * 200 + h];
  } else if (i < WS_WIST) {
    int q = i - WS_WIMT; int c = q / 200, k = q - c * 200;
    v = w_imean[k * 30 + c];
  } else if (i < WS_WOMT) {
    int q = i - WS_WIST; int c = q / 200, k = q - c * 200;
    v = w_istd[k * 30 + c];
  } else if (i < WS_WOST) {
    int q = i - WS_WOMT; int c = q / 200, k = q - c * 200;
    v = w_omean[k * 30 + c];
  } else if (i < WS_TOTAL_BF) {
    int q = i - WS_WOST; int c = q / 200, k = q - c * 200;
    v = w_ostd[k * 30 + c];
  } else return;
  o[i] = (__bf16)v;
}

// ---------------------------------------------------------------------------
// K1: xpre[t][b][h] = embed[b*64+t, :] @ w_obs1[200:1224, :] + b_obs1
// M=65536 (block = one b, rows = t 0..63), N=208 (200 + pad), K=1024.
// mfma_f32_16x16x32_bf16.  A frag: A[m=lane&15][k=quad*8+j];
// B frag: B[k=quad*8+j][n=lane&15];  C/D: row=quad*4+reg, col=lane&15.
// ---------------------------------------------------------------------------
__global__ __launch_bounds__(256) void k1_embed_gemm(
    const float* __restrict__ embed,   // [B*T][1024]
    const __bf16* __restrict__ wT,     // [208][1024]  n-major, k-contiguous
    const float* __restrict__ b_obs1,  // [200]
    float* __restrict__ xpre)          // [64][1024][200]
{
  __shared__ __align__(16) __bf16 As[64][72];    // +8 pad: 2-way banks
  __shared__ __align__(16) __bf16 Bs[208][72];
  int tid = threadIdx.x;
  int b = blockIdx.x;
  int wave = tid >> 6, lane = tid & 63;
  int lm = lane & 15, quad = lane >> 4;

  f32x4 acc[13];
#pragma unroll
  for (int n = 0; n < 13; ++n) acc[n] = (f32x4){0.f, 0.f, 0.f, 0.f};

  const float* arow_base = embed + (size_t)b * 64 * 1024;

  for (int ko = 0; ko < 1024; ko += 64) {
    // stage A tile: 64 rows x 64 k, fp32 -> bf16
#pragma unroll
    for (int p = 0; p < 4; ++p) {
      int v = p * 256 + tid; int row = v >> 4; int c4 = v & 15;
      float4 f = *(const float4*)(arow_base + (size_t)row * 1024 + ko + c4 * 4);
      __bf16* dst = &As[row][c4 * 4];
      dst[0] = (__bf16)f.x; dst[1] = (__bf16)f.y;
      dst[2] = (__bf16)f.z; dst[3] = (__bf16)f.w;
    }
    // stage B tile: 208 n-rows x 64 k (already bf16, n-major)
#pragma unroll
    for (int p = 0; p < 13; ++p) {
      int v = p * 256 + tid; int n = v >> 4; int c4 = v & 15;
      ushort4 u = *(const ushort4*)(wT + (size_t)n * 1024 + ko + c4 * 4);
      *(ushort4*)&Bs[n][c4 * 4] = u;
    }
    __syncthreads();
#pragma unroll
    for (int kc = 0; kc < 2; ++kc) {
      bf16x8 a = *(const bf16x8*)&As[16 * wave + lm][kc * 32 + quad * 8];
#pragma unroll
      for (int n = 0; n < 13; ++n) {
        bf16x8 bb = *(const bf16x8*)&Bs[16 * n + lm][kc * 32 + quad * 8];
        acc[n] = __builtin_amdgcn_mfma_f32_16x16x32_bf16(a, bb, acc[n], 0, 0, 0);
      }
    }
    __syncthreads();
  }
  // epilogue: add bias, store (skip pad cols >= 200)
  int trow_base = 16 * wave + quad * 4;
#pragma unroll
  for (int n = 0; n < 13; ++n) {
    int col = n * 16 + lm;
    if (col < 200) {
      float bias = b_obs1[col];
#pragma unroll
      for (int r = 0; r < 4; ++r) {
        int trow = trow_base + r;
        xpre[(size_t)trow * (1024 * 200) + (size_t)b * 200 + col] = acc[n][r] + bias;
      }
    }
  }
}

// ---------------------------------------------------------------------------
// K2: persistent recurrent kernel.  256 blocks x 512 threads, 4 batch rows
// each, loops t=0..63 with LDS state.  bf16 weights, fp32 activations/acc.
// ---------------------------------------------------------------------------
__global__ __launch_bounds__(512) void k2_recurrent(
    const float* __restrict__ action,       // [B][64][6]
    const float* __restrict__ noise_prior,  // [64][B][30]
    const float* __restrict__ noise_post,   // [64][B][30]
    const float* __restrict__ b_img1, const float* __restrict__ gru_b,
    const float* __restrict__ gru_rb, const float* __restrict__ b_img2,
    const float* __restrict__ b_imean, const float* __restrict__ b_istd,
    const float* __restrict__ b_omean, const float* __restrict__ b_ostd,
    const __bf16* __restrict__ w1T,   // [200][36]
    const __bf16* __restrict__ gwT,   // [600][200]
    const __bf16* __restrict__ guT,   // [600][200]
    const __bf16* __restrict__ w2T,   // [200][200]
    const __bf16* __restrict__ wodT,  // [200][200]
    const __bf16* __restrict__ wimT, const __bf16* __restrict__ wisT, // [30][200]
    const __bf16* __restrict__ womT, const __bf16* __restrict__ wosT, // [30][200]
    const float* __restrict__ xpre,   // [64][B][200]
    float* __restrict__ out)          // [B][64][580]
{
  __shared__ __align__(16) float stoch[4][32];
  __shared__ __align__(16) float deter[4][200];
  __shared__ __align__(16) float xbuf[4][200];
  __shared__ __align__(16) float gbuf[4][1200];   // [xg(600) | hg(600)]
  __shared__ __align__(16) float x2b[4][200];
  __shared__ __align__(16) float xob[4][200];
  __shared__ __align__(16) float abuf[4][8];
  __shared__ __align__(16) float hm[4][4][30];    // om, os_raw, pm, ps_raw

  const int tid = threadIdx.x;
  const int b0 = blockIdx.x * 4;

  for (int i = tid; i < 4 * 32; i += 512) ((float*)stoch)[i] = 0.f;
  for (int i = tid; i < 4 * 200; i += 512) ((float*)deter)[i] = 0.f;
  __syncthreads();

  for (int t = 0; t < 64; ++t) {
    // ---- load action for this step
    if (tid < 24) {
      int r = tid / 6, k = tid - r * 6;
      abuf[r][k] = action[(size_t)(b0 + r) * 384 + t * 6 + k];
    }
    __syncthreads();  // S1

    // ---- phase A: x = elu([stoch, a] @ w_img1 + b_img1)
    if (tid < 200) {
      int h = tid;
      const __bf16* wrow = w1T + h * 36;
      float bv = b_img1[h];
      float acc[4] = {bv, bv, bv, bv};
#pragma unroll
      for (int k = 0; k < 30; ++k) {
        float w = (float)wrow[k];
#pragma unroll
        for (int r = 0; r < 4; ++r) acc[r] = fmaf(stoch[r][k], w, acc[r]);
      }
#pragma unroll
      for (int k = 0; k < 6; ++k) {
        float w = (float)wrow[30 + k];
#pragma unroll
        for (int r = 0; r < 4; ++r) acc[r] = fmaf(abuf[r][k], w, acc[r]);
      }
#pragma unroll
      for (int r = 0; r < 4; ++r) xbuf[r][h] = elu1(acc[r]);
    }
    __syncthreads();  // S2

    // ---- phase B: xg = x @ gru_w + gru_b ; hg = deter @ gru_u + gru_rb
#pragma unroll 1
    for (int pass = 0; pass < 2; ++pass) {
      const __bf16* wT = pass ? guT : gwT;
      const float* inb = pass ? &deter[0][0] : &xbuf[0][0];
      const float* bias = pass ? gru_rb : gru_b;
      int j1 = tid;             // < 512 < 600
      int j2 = tid + 512;
      bool has2 = (j2 < 600);
      float bv1 = bias[j1];
      float bv2 = has2 ? bias[j2] : 0.f;
      float acc1[4] = {bv1, bv1, bv1, bv1};
      float acc2[4] = {bv2, bv2, bv2, bv2};
      const __bf16* w1r = wT + j1 * 200;
      const __bf16* w2r = wT + (has2 ? j2 : j1) * 200;
      for (int kb = 0; kb < 25; ++kb) {
        float inv[4][8];
#pragma unroll
        for (int r = 0; r < 4; ++r) {
          float4 lo = *(const float4*)(inb + r * 200 + kb * 8);
          float4 hi = *(const float4*)(inb + r * 200 + kb * 8 + 4);
          inv[r][0] = lo.x; inv[r][1] = lo.y; inv[r][2] = lo.z; inv[r][3] = lo.w;
          inv[r][4] = hi.x; inv[r][5] = hi.y; inv[r][6] = hi.z; inv[r][7] = hi.w;
        }
        bf16x8 wa = *(const bf16x8*)(w1r + kb * 8);
        bf16x8 wb = *(const bf16x8*)(w2r + kb * 8);
#pragma unroll
        for (int q = 0; q < 8; ++q) {
          float f1 = (float)wa[q];
          float f2 = (float)wb[q];
#pragma unroll
          for (int r = 0; r < 4; ++r) {
            acc1[r] = fmaf(inv[r][q], f1, acc1[r]);
            acc2[r] = fmaf(inv[r][q], f2, acc2[r]);
          }
        }
      }
      int off = pass * 600;
#pragma unroll
      for (int r = 0; r < 4; ++r) gbuf[r][off + j1] = acc1[r];
      if (has2) {
#pragma unroll
        for (int r = 0; r < 4; ++r) gbuf[r][off + j2] = acc2[r];
      }
    }
    __syncthreads();  // S3

    // ---- phase C1: GRU combine, write deter_n to state + output
    for (int idx = tid; idx < 800; idx += 512) {
      int r = idx / 200, d = idx - r * 200;
      float xz = gbuf[r][d],       xr_ = gbuf[r][200 + d], xh = gbuf[r][400 + d];
      float hz = gbuf[r][600 + d], hr_ = gbuf[r][800 + d], hh = gbuf[r][1000 + d];
      float z  = sigm(xz + hz);
      float rr = sigm(xr_ + hr_);
      float hc = tanhf(xh + rr * hh);
      float dn = z * deter[r][d] + (1.f - z) * hc;
      deter[r][d] = dn;
      size_t ob = ((size_t)(b0 + r) * 64 + t) * 580;
      out[ob + 90 + d] = dn;
      out[ob + 380 + d] = dn;
    }
    __syncthreads();  // S4

    // ---- phase C2: x2 = elu(deter_n @ w_img2 + b) ; xo = elu(deter_n @ w_od + xpre)
    if (tid < 400) {
      int isobs = (tid >= 200) ? 1 : 0;
      int h = tid - isobs * 200;
      float acc[4];
      if (isobs) {
#pragma unroll
        for (int r = 0; r < 4; ++r)
          acc[r] = xpre[((size_t)t * 1024 + (b0 + r)) * 200 + h];
      } else {
        float bv = b_img2[h];
#pragma unroll
        for (int r = 0; r < 4; ++r) acc[r] = bv;
      }
      const __bf16* wrow = (isobs ? wodT : w2T) + h * 200;
      for (int kb = 0; kb < 25; ++kb) {
        float inv[4][8];
#pragma unroll
        for (int r = 0; r < 4; ++r) {
          float4 lo = *(const float4*)(&deter[r][0] + kb * 8);
          float4 hi = *(const float4*)(&deter[r][0] + kb * 8 + 4);
          inv[r][0] = lo.x; inv[r][1] = lo.y; inv[r][2] = lo.z; inv[r][3] = lo.w;
          inv[r][4] = hi.x; inv[r][5] = hi.y; inv[r][6] = hi.z; inv[r][7] = hi.w;
        }
        bf16x8 wv = *(const bf16x8*)(wrow + kb * 8);
#pragma unroll
        for (int q = 0; q < 8; ++q) {
          float w = (float)wv[q];
#pragma unroll
          for (int r = 0; r < 4; ++r) acc[r] = fmaf(inv[r][q], w, acc[r]);
        }
      }
#pragma unroll
      for (int r = 0; r < 4; ++r) {
        float v = elu1(acc[r]);
        if (isobs) xob[r][h] = v; else x2b[r][h] = v;
      }
    }
    __syncthreads();  // S5

    // ---- phase D: 4 heads (omean, ostd, pmean, pstd), raw preacts into hm
    if (tid < 240) {
      int hd = tid / 60, sub = tid - hd * 60;
      int c = sub >> 1, r0 = (sub & 1) * 2;
      const float* inb = (hd < 2) ? &xob[0][0] : &x2b[0][0];
      const __bf16* wT_ = (hd == 0) ? womT : (hd == 1) ? wosT : (hd == 2) ? wimT : wisT;
      const float* bs_  = (hd == 0) ? b_omean : (hd == 1) ? b_ostd : (hd == 2) ? b_imean : b_istd;
      float a0 = bs_[c], a1 = a0;
      const __bf16* wrow = wT_ + c * 200;
      for (int kb = 0; kb < 25; ++kb) {
        float4 lo0 = *(const float4*)(inb + r0 * 200 + kb * 8);
        float4 hi0 = *(const float4*)(inb + r0 * 200 + kb * 8 + 4);
        float4 lo1 = *(const float4*)(inb + (r0 + 1) * 200 + kb * 8);
        float4 hi1 = *(const float4*)(inb + (r0 + 1) * 200 + kb * 8 + 4);
        float i0[8] = {lo0.x, lo0.y, lo0.z, lo0.w, hi0.x, hi0.y, hi0.z, hi0.w};
        float i1[8] = {lo1.x, lo1.y, lo1.z, lo1.w, hi1.x, hi1.y, hi1.z, hi1.w};
        bf16x8 wv = *(const bf16x8*)(wrow + kb * 8);
#pragma unroll
        for (int q = 0; q < 8; ++q) {
          float w = (float)wv[q];
          a0 = fmaf(i0[q], w, a0);
          a1 = fmaf(i1[q], w, a1);
        }
      }
      hm[hd][r0][c] = a0;
      hm[hd][r0 + 1][c] = a1;
    }
    __syncthreads();  // S6

    // ---- phase E: nonlinearities, stochastic sample, output, next stoch
    if (tid < 120) {
      int r = tid / 30, c = tid - r * 30;
      float om = hm[0][r][c];
      float os = spls(hm[1][r][c]);           // NOTE: no +0.1 on ostd
      float pm = hm[2][r][c];
      float ps = spls(hm[3][r][c]) + 0.1f;    // +0.1 on pstd only
      float nzo = noise_post [(size_t)t * (1024 * 30) + (b0 + r) * 30 + c];
      float nzp = noise_prior[(size_t)t * (1024 * 30) + (b0 + r) * 30 + c];
      float ost = om + os * nzo;
      float pst = pm + ps * nzp;
      stoch[r][c] = ost;                      // carry = posterior stoch
      size_t ob = ((size_t)(b0 + r) * 64 + t) * 580;
      out[ob + c]        = om;
      out[ob + 30 + c]   = os;
      out[ob + 60 + c]   = ost;
      out[ob + 290 + c]  = pm;
      out[ob + 320 + c]  = ps;
      out[ob + 350 + c]  = pst;
    }
    __syncthreads();  // S7: stoch ready for next step's phase A
  }
}

// ---------------------------------------------------------------------------
extern "C" void kernel_launch(void* const* d_in, const int* in_sizes, int n_in,
                              void* d_out, int out_size, void* d_ws, size_t ws_size,
                              hipStream_t stream) {
  const float* embed   = (const float*)d_in[0];
  const float* action  = (const float*)d_in[1];
  const float* nzp     = (const float*)d_in[2];
  const float* nzo     = (const float*)d_in[3];
  const float* w_img1  = (const float*)d_in[4];
  const float* b_img1  = (const float*)d_in[5];
  const float* gru_w   = (const float*)d_in[6];
  const float* gru_u   = (const float*)d_in[7];
  const float* gru_b   = (const float*)d_in[8];
  const float* gru_rb  = (const float*)d_in[9];
  const float* w_img2  = (const float*)d_in[10];
  const float* b_img2  = (const float*)d_in[11];
  const float* w_imean = (const float*)d_in[12];
  const float* b_imean = (const float*)d_in[13];
  const float* w_istd  = (const float*)d_in[14];
  const float* b_istd  = (const float*)d_in[15];
  const float* w_obs1  = (const float*)d_in[16];
  const float* b_obs1  = (const float*)d_in[17];
  const float* w_omean = (const float*)d_in[18];
  const float* b_omean = (const float*)d_in[19];
  const float* w_ostd  = (const float*)d_in[20];
  const float* b_ostd  = (const float*)d_in[21];
  float* out = (float*)d_out;

  __bf16* wbf = (__bf16*)d_ws;
  float* xpre = (float*)((char*)d_ws + WS_XPRE_BYTES);

  k0_convert<<<(WS_TOTAL_BF + 255) / 256, 256, 0, stream>>>(
      w_img1, gru_w, gru_u, w_img2, w_imean, w_istd, w_obs1, w_omean, w_ostd, wbf);

  k1_embed_gemm<<<1024, 256, 0, stream>>>(embed, wbf, b_obs1, xpre);

  k2_recurrent<<<256, 512, 0, stream>>>(
      action, nzp, nzo,
      b_img1, gru_b, gru_rb, b_img2, b_imean, b_istd, b_omean, b_ostd,
      wbf + WS_W1T, wbf + WS_GWT, wbf + WS_GUT, wbf + WS_W2T, wbf + WS_WODT,
      wbf + WS_WIMT, wbf + WS_WIST, wbf + WS_WOMT, wbf + WS_WOST,
      xpre, out);
}

// Round 2
// 1887.708 us; speedup vs baseline: 1.7235x; 1.7235x over previous
//
#include <hip/hip_runtime.h>
#include <cstddef>

// ---------------------------------------------------------------------------
// RSSM observe. R2: MFMA-based recurrent kernel.
//   K0: weight convert/transpose to bf16, K-padded to 224 (zeros) so A-side
//       LDS pads never contaminate results.
//   K1: embed-part of obs1 precomputed as bf16 MFMA GEMM (unchanged from R1).
//   K2: 64 blocks x 16 batch rows x 512 threads (8 waves). All dense layers
//       via mfma_f32_16x16x32_bf16, M=16 (one m-tile). B-fragments streamed
//       from L2-resident global weights. Activations bf16 in LDS.
//
// ws layout (bf16 elements unless noted):
//   [0,       212992)  k1wT   [208][1024]  (K1 B operand)
//   [212992,  226304)  w1T    [208][64]
//   [226304,  362496)  gwT    [608][224]
//   [362496,  498688)  guT    [608][224]
//   [498688,  591872)  wcT    [416][224]   (w_img2 rows 0..199, w_obs1-deter rows 208..407)
//   [591872,  620544)  whT    [128][224]   (omean/ostd/imean/istd, 32 rows each)
//   bytes [1241088, +52428800) xpre fp32 [64][1024][200]
// ---------------------------------------------------------------------------

typedef __bf16 bf16x8 __attribute__((ext_vector_type(8)));
typedef float  f32x4  __attribute__((ext_vector_type(4)));

#define OFF_K1WT 0
#define OFF_W1T  212992
#define OFF_GWT  226304
#define OFF_GUT  362496
#define OFF_WCT  498688
#define OFF_WHT  591872
#define WS_BF_TOTAL 620544
#define WS_XPRE_BYTES 1241088   // WS_BF_TOTAL * 2

__device__ __forceinline__ float elu1(float v){ return v > 0.f ? v : expm1f(v); }
__device__ __forceinline__ float sigm(float v){ return 1.f / (1.f + expf(-v)); }
__device__ __forceinline__ float spls(float v){ return fmaxf(v,0.f) + log1pf(expf(-fabsf(v))); }

// ---------------------------------------------------------------------------
// K0: weight conversion + transpose + K-padding.
// ---------------------------------------------------------------------------
__global__ __launch_bounds__(256) void k0_convert(
    const float* __restrict__ w_img1, const float* __restrict__ gru_w,
    const float* __restrict__ gru_u,  const float* __restrict__ w_img2,
    const float* __restrict__ w_imean, const float* __restrict__ w_istd,
    const float* __restrict__ w_obs1, const float* __restrict__ w_omean,
    const float* __restrict__ w_ostd, __bf16* __restrict__ o)
{
  int i = blockIdx.x * 256 + threadIdx.x;
  if (i >= WS_BF_TOTAL) return;
  float v = 0.f;
  if (i < OFF_W1T) {                       // k1wT[n][k] = w_obs1[200+k][n]
    int n = i >> 10, k = i & 1023;
    v = (n < 200) ? w_obs1[(size_t)(200 + k) * 200 + n] : 0.f;
  } else if (i < OFF_GWT) {                // w1T[n][k] = w_img1[k][n]
    int q = i - OFF_W1T; int n = q >> 6, k = q & 63;
    if (n < 200 && k < 36) v = w_img1[k * 200 + n];
  } else if (i < OFF_GUT) {                // gwT[j][k] = gru_w[k][j]
    int q = i - OFF_GWT; int j = q / 224, k = q - j * 224;
    if (j < 600 && k < 200) v = gru_w[k * 600 + j];
  } else if (i < OFF_WCT) {                // guT[j][k] = gru_u[k][j]
    int q = i - OFF_GUT; int j = q / 224, k = q - j * 224;
    if (j < 600 && k < 200) v = gru_u[k * 600 + j];
  } else if (i < OFF_WHT) {                // wcT: img2 rows 0..199, obs1-deter rows 208..407
    int q = i - OFF_WCT; int n = q / 224, k = q - n * 224;
    if (k < 200) {
      if (n < 200)                 v = w_img2[k * 200 + n];
      else if (n >= 208 && n < 408) v = w_obs1[k * 200 + (n - 208)];
    }
  } else {                                 // whT: heads, 32 rows each
    int q = i - OFF_WHT; int n = q / 224, k = q - n * 224;
    int h = n >> 5, c = n & 31;
    if (k < 200 && c < 30) {
      const float* wh = (h == 0) ? w_omean : (h == 1) ? w_ostd : (h == 2) ? w_imean : w_istd;
      v = wh[k * 30 + c];
    }
  }
  o[i] = (__bf16)v;
}

// ---------------------------------------------------------------------------
// K1: xpre[t][b][h] = embed[b*64+t,:] @ w_obs1[200:1224,:] + b_obs1  (as R1)
// ---------------------------------------------------------------------------
__global__ __launch_bounds__(256) void k1_embed_gemm(
    const float* __restrict__ embed, const __bf16* __restrict__ wT,
    const float* __restrict__ b_obs1, float* __restrict__ xpre)
{
  __shared__ __align__(16) __bf16 As[64][72];
  __shared__ __align__(16) __bf16 Bs[208][72];
  int tid = threadIdx.x;
  int b = blockIdx.x;
  int wave = tid >> 6, lane = tid & 63;
  int lm = lane & 15, quad = lane >> 4;

  f32x4 acc[13];
#pragma unroll
  for (int n = 0; n < 13; ++n) acc[n] = (f32x4){0.f, 0.f, 0.f, 0.f};

  const float* arow_base = embed + (size_t)b * 64 * 1024;

  for (int ko = 0; ko < 1024; ko += 64) {
#pragma unroll
    for (int p = 0; p < 4; ++p) {
      int v = p * 256 + tid; int row = v >> 4; int c4 = v & 15;
      float4 f = *(const float4*)(arow_base + (size_t)row * 1024 + ko + c4 * 4);
      __bf16* dst = &As[row][c4 * 4];
      dst[0] = (__bf16)f.x; dst[1] = (__bf16)f.y;
      dst[2] = (__bf16)f.z; dst[3] = (__bf16)f.w;
    }
#pragma unroll
    for (int p = 0; p < 13; ++p) {
      int v = p * 256 + tid; int n = v >> 4; int c4 = v & 15;
      ushort4 u = *(const ushort4*)(wT + (size_t)n * 1024 + ko + c4 * 4);
      *(ushort4*)&Bs[n][c4 * 4] = u;
    }
    __syncthreads();
#pragma unroll
    for (int kc = 0; kc < 2; ++kc) {
      bf16x8 a = *(const bf16x8*)&As[16 * wave + lm][kc * 32 + quad * 8];
#pragma unroll
      for (int n = 0; n < 13; ++n) {
        bf16x8 bb = *(const bf16x8*)&Bs[16 * n + lm][kc * 32 + quad * 8];
        acc[n] = __builtin_amdgcn_mfma_f32_16x16x32_bf16(a, bb, acc[n], 0, 0, 0);
      }
    }
    __syncthreads();
  }
  int trow_base = 16 * wave + quad * 4;
#pragma unroll
  for (int n = 0; n < 13; ++n) {
    int col = n * 16 + lm;
    if (col < 200) {
      float bias = b_obs1[col];
#pragma unroll
      for (int r = 0; r < 4; ++r) {
        int trow = trow_base + r;
        xpre[(size_t)trow * (1024 * 200) + (size_t)b * 200 + col] = acc[n][r] + bias;
      }
    }
  }
}

// ---------------------------------------------------------------------------
// K2: MFMA recurrent kernel.  64 blocks x 512 threads, 16 batch rows/block.
// ---------------------------------------------------------------------------
__global__ __launch_bounds__(512) void k2_recurrent(
    const float* __restrict__ action, const float* __restrict__ noise_prior,
    const float* __restrict__ noise_post,
    const float* __restrict__ b_img1, const float* __restrict__ gru_b,
    const float* __restrict__ gru_rb, const float* __restrict__ b_img2,
    const float* __restrict__ b_imean, const float* __restrict__ b_istd,
    const float* __restrict__ b_omean, const float* __restrict__ b_ostd,
    const __bf16* __restrict__ w1T, const __bf16* __restrict__ gwT,
    const __bf16* __restrict__ guT, const __bf16* __restrict__ wcT,
    const __bf16* __restrict__ whT,
    const float* __restrict__ xpre, float* __restrict__ out)
{
  // A-operand buffers: row stride chosen for 16B alignment + <=2-way banks.
  __shared__ __align__(16) __bf16 actin[16][72];   // [stoch(30)|action(6)|pad->64|slack]
  __shared__ __align__(16) __bf16 xbuf[16][232];   // x (img1 out), K-pad 200..223 = 0
  __shared__ __align__(16) __bf16 dbuf[16][232];   // deter carry (bf16)
  __shared__ __align__(16) char   ovl[39168];      // ggbuf bf16[16][1224]  OR  {x2b,xob,[16][132]f32 headbuf}
  __shared__ float biasL[1760];  // [0:208) img1 | [208:816) gru_b | [816:1424) gru_rb | [1424:1632) img2 | [1632:1760) heads

  const int tid  = threadIdx.x;
  const int wv   = tid >> 6;
  const int lane = tid & 63;
  const int lm   = lane & 15, quad = lane >> 4;
  const int b0   = blockIdx.x * 16;

  __bf16* gg    = (__bf16*)ovl;                 // stride 1224
  __bf16* x2b   = (__bf16*)ovl;                 // stride 232
  __bf16* xob   = (__bf16*)(ovl + 7424);        // stride 232
  float*  headb = (float*)(ovl + 14848);        // stride 132

  // ---- init: zero A-buffers (incl. K-pads), load biases, load action[0]
  for (int i = tid; i < 16 * 72; i += 512) {
    int m = i / 72, c = i - m * 72;
    if (c < 30 || c >= 36) actin[m][c] = (__bf16)0.f;
  }
  for (int i = tid; i < 16 * 232; i += 512) { ((__bf16*)xbuf)[i] = (__bf16)0.f; ((__bf16*)dbuf)[i] = (__bf16)0.f; }
  for (int i = tid; i < 1760; i += 512) {
    float v = 0.f;
    if (i < 208)       { if (i < 200) v = b_img1[i]; }
    else if (i < 816)  { int j = i - 208;  if (j < 600) v = gru_b[j]; }
    else if (i < 1424) { int j = i - 816;  if (j < 600) v = gru_rb[j]; }
    else if (i < 1632) { int j = i - 1424; if (j < 200) v = b_img2[j]; }
    else { int n = i - 1632; int h = n >> 5, c = n & 31;
           if (c < 30) v = ((h == 0) ? b_omean : (h == 1) ? b_ostd : (h == 2) ? b_imean : b_istd)[c]; }
    biasL[i] = v;
  }
  if (tid < 96) {
    int m = tid / 6, k = tid - m * 6;
    actin[m][30 + k] = (__bf16)action[(size_t)(b0 + m) * 384 + k];
  }
  __syncthreads();

  for (int t = 0; t < 64; ++t) {
    // ---- phase A: x = elu([stoch,a] @ w_img1 + b)   (13 n-tiles, K=64)
    for (int tt = wv; tt < 13; tt += 8) {
      const __bf16* bw = w1T + (tt * 16 + lm) * 64 + quad * 8;
      bf16x8 a0 = *(const bf16x8*)&actin[lm][quad * 8];
      bf16x8 a1 = *(const bf16x8*)&actin[lm][32 + quad * 8];
      bf16x8 bv0 = *(const bf16x8*)(bw);
      bf16x8 bv1 = *(const bf16x8*)(bw + 32);
      f32x4 c = (f32x4){0.f, 0.f, 0.f, 0.f};
      c = __builtin_amdgcn_mfma_f32_16x16x32_bf16(a0, bv0, c, 0, 0, 0);
      c = __builtin_amdgcn_mfma_f32_16x16x32_bf16(a1, bv1, c, 0, 0, 0);
      int col = tt * 16 + lm;
      float bias = biasL[col];
      if (col < 200) {
#pragma unroll
        for (int r = 0; r < 4; ++r) xbuf[quad * 4 + r][col] = (__bf16)elu1(c[r] + bias);
      }
    }
    __syncthreads();  // S2

    // ---- phase B: waves 0..3: xg = x@gru_w ; waves 4..7: hg = deter@gru_u
    {
      const int gsel = wv >> 2, wsub = wv & 3;
      const __bf16* WT    = gsel ? guT : gwT;
      const __bf16* Abase = gsel ? &dbuf[0][0] : &xbuf[0][0];
      const int cbase = gsel ? 608 : 0;
      const int bbase = gsel ? 816 : 208;
      bf16x8 af[7];
#pragma unroll
      for (int k = 0; k < 7; ++k) af[k] = *(const bf16x8*)(Abase + lm * 232 + k * 32 + quad * 8);
      for (int tt = wsub; tt < 38; tt += 4) {
        const __bf16* bw = WT + (tt * 16 + lm) * 224 + quad * 8;
        f32x4 c = (f32x4){0.f, 0.f, 0.f, 0.f};
#pragma unroll
        for (int k = 0; k < 7; ++k) {
          bf16x8 bv = *(const bf16x8*)(bw + k * 32);
          c = __builtin_amdgcn_mfma_f32_16x16x32_bf16(af[k], bv, c, 0, 0, 0);
        }
        int col = tt * 16 + lm;
        float bias = biasL[bbase + col];
#pragma unroll
        for (int r = 0; r < 4; ++r) gg[(quad * 4 + r) * 1224 + cbase + col] = (__bf16)(c[r] + bias);
      }
    }
    __syncthreads();  // S3

    // ---- phase C1: GRU combine -> deter (bf16 carry) + out
    for (int idx = tid; idx < 3200; idx += 512) {
      int m = idx / 200, d = idx - m * 200;
      const __bf16* row = gg + m * 1224;
      float xz = (float)row[d],        xr_ = (float)row[200 + d], xh = (float)row[400 + d];
      float hz = (float)row[608 + d],  hr_ = (float)row[808 + d], hh = (float)row[1008 + d];
      float z  = sigm(xz + hz);
      float rr = sigm(xr_ + hr_);
      float hc = tanhf(xh + rr * hh);
      float dn = z * (float)dbuf[m][d] + (1.f - z) * hc;
      dbuf[m][d] = (__bf16)dn;
      size_t ob = ((size_t)(b0 + m) * 64 + t) * 580;
      out[ob + 90 + d]  = dn;
      out[ob + 380 + d] = dn;
    }
    __syncthreads();  // S4

    // ---- phase C2: x2 = elu(d@w_img2+b) ; xo = elu(d@w_obs1_d + xpre)
    {
      bf16x8 df[7];
#pragma unroll
      for (int k = 0; k < 7; ++k) df[k] = *(const bf16x8*)(&dbuf[lm][0] + k * 32 + quad * 8);
      for (int tt = wv; tt < 26; tt += 8) {
        const __bf16* bw = wcT + (tt * 16 + lm) * 224 + quad * 8;
        f32x4 c = (f32x4){0.f, 0.f, 0.f, 0.f};
#pragma unroll
        for (int k = 0; k < 7; ++k) {
          bf16x8 bv = *(const bf16x8*)(bw + k * 32);
          c = __builtin_amdgcn_mfma_f32_16x16x32_bf16(df[k], bv, c, 0, 0, 0);
        }
        if (tt < 13) {
          int col = tt * 16 + lm;
          float bias = biasL[1424 + col];
          if (col < 200) {
#pragma unroll
            for (int r = 0; r < 4; ++r) x2b[(quad * 4 + r) * 232 + col] = (__bf16)elu1(c[r] + bias);
          }
        } else {
          int col = (tt - 13) * 16 + lm;
          if (col < 200) {
#pragma unroll
            for (int r = 0; r < 4; ++r) {
              int m2 = quad * 4 + r;
              float pre = c[r] + xpre[((size_t)t * 1024 + b0 + m2) * 200 + col];
              xob[m2 * 232 + col] = (__bf16)elu1(pre);
            }
          }
        }
      }
    }
    __syncthreads();  // S5

    // ---- phase D: heads.  wave wv handles tile wv; tiles 0..3 <- xo, 4..7 <- x2
    {
      const __bf16* Ab = (wv < 4) ? xob : x2b;
      bf16x8 hf[7];
#pragma unroll
      for (int k = 0; k < 7; ++k) hf[k] = *(const bf16x8*)(Ab + lm * 232 + k * 32 + quad * 8);
      const __bf16* bw = whT + (wv * 16 + lm) * 224 + quad * 8;
      f32x4 c = (f32x4){0.f, 0.f, 0.f, 0.f};
#pragma unroll
      for (int k = 0; k < 7; ++k) {
        bf16x8 bv = *(const bf16x8*)(bw + k * 32);
        c = __builtin_amdgcn_mfma_f32_16x16x32_bf16(hf[k], bv, c, 0, 0, 0);
      }
      int n = wv * 16 + lm;
      float bias = biasL[1632 + n];
#pragma unroll
      for (int r = 0; r < 4; ++r) headb[(quad * 4 + r) * 132 + n] = c[r] + bias;
    }
    __syncthreads();  // S6

    // ---- phase E: nonlinearities + sample + outputs + next stoch/action
    if (tid < 480) {
      int m = tid / 30, c = tid - m * 30;
      const float* hb = headb + m * 132;
      float om = hb[c], osr = hb[32 + c], pm = hb[64 + c], psr = hb[96 + c];
      float os = spls(osr);               // obs: no +0.1
      float ps = spls(psr) + 0.1f;        // img: +0.1
      float nzo = noise_post [(size_t)t * 30720 + (b0 + m) * 30 + c];
      float nzp = noise_prior[(size_t)t * 30720 + (b0 + m) * 30 + c];
      float ost = om + os * nzo;
      float pst = pm + ps * nzp;
      actin[m][c] = (__bf16)ost;          // next stoch (bf16 carry)
      size_t ob = ((size_t)(b0 + m) * 64 + t) * 580;
      out[ob + c]       = om;
      out[ob + 30 + c]  = os;
      out[ob + 60 + c]  = ost;
      out[ob + 290 + c] = pm;
      out[ob + 320 + c] = ps;
      out[ob + 350 + c] = pst;
    } else if (t < 63) {
      for (int j = tid - 480; j < 96; j += 32) {
        int m = j / 6, k = j - m * 6;
        actin[m][30 + k] = (__bf16)action[(size_t)(b0 + m) * 384 + (t + 1) * 6 + k];
      }
    }
    __syncthreads();  // S7
  }
}

// ---------------------------------------------------------------------------
extern "C" void kernel_launch(void* const* d_in, const int* in_sizes, int n_in,
                              void* d_out, int out_size, void* d_ws, size_t ws_size,
                              hipStream_t stream) {
  const float* embed   = (const float*)d_in[0];
  const float* action  = (const float*)d_in[1];
  const float* nzp     = (const float*)d_in[2];
  const float* nzo     = (const float*)d_in[3];
  const float* w_img1  = (const float*)d_in[4];
  const float* b_img1  = (const float*)d_in[5];
  const float* gru_w   = (const float*)d_in[6];
  const float* gru_u   = (const float*)d_in[7];
  const float* gru_b   = (const float*)d_in[8];
  const float* gru_rb  = (const float*)d_in[9];
  const float* w_img2  = (const float*)d_in[10];
  const float* b_img2  = (const float*)d_in[11];
  const float* w_imean = (const float*)d_in[12];
  const float* b_imean = (const float*)d_in[13];
  const float* w_istd  = (const float*)d_in[14];
  const float* b_istd  = (const float*)d_in[15];
  const float* w_obs1  = (const float*)d_in[16];
  const float* b_obs1  = (const float*)d_in[17];
  const float* w_omean = (const float*)d_in[18];
  const float* b_omean = (const float*)d_in[19];
  const float* w_ostd  = (const float*)d_in[20];
  const float* b_ostd  = (const float*)d_in[21];
  float* out = (float*)d_out;

  __bf16* wbf = (__bf16*)d_ws;
  float* xpre = (float*)((char*)d_ws + WS_XPRE_BYTES);

  k0_convert<<<(WS_BF_TOTAL + 255) / 256, 256, 0, stream>>>(
      w_img1, gru_w, gru_u, w_img2, w_imean, w_istd, w_obs1, w_omean, w_ostd, wbf);

  k1_embed_gemm<<<1024, 256, 0, stream>>>(embed, wbf + OFF_K1WT, b_obs1, xpre);

  k2_recurrent<<<64, 512, 0, stream>>>(
      action, nzp, nzo,
      b_img1, gru_b, gru_rb, b_img2, b_imean, b_istd, b_omean, b_ostd,
      wbf + OFF_W1T, wbf + OFF_GWT, wbf + OFF_GUT, wbf + OFF_WCT, wbf + OFF_WHT,
      xpre, out);
}